// Round 13
// baseline (286.142 us; speedup 1.0000x reference)
//
#include <hip/hip_runtime.h>

#define CCH 32
#define BCH 6
#define HH  180
#define WW  320
#define NN  (HH*WW)             // 57600
#define BATCH 32
#define RPC 8                    // rows per chunk
#define CHUNKS ((HH + RPC - 1)/RPC)   // 23 (last chunk: 4 rows, strip2 guarded off)
#define THREADS 320              // 5 waves; 8 px per thread = 2 strips of 4 px
#define NXCD 8
#define GRID_MAIN (NXCD * 3 * BATCH)  // 768: each XCD gets 3 chunk-slots x 32 b

typedef float f32x2 __attribute__((ext_vector_type(2)));
typedef float f32x4 __attribute__((ext_vector_type(4)));

// ---- kernel A: se_r[c][p] = se[c][walk-strip(p)] + b_deflat[c]
__global__ __launch_bounds__(256) void permute_se(
    const float* __restrict__ se, const int* __restrict__ unwalk,
    const float* __restrict__ b_deflat, float* __restrict__ se_r)
{
    const int p = (blockIdx.x * 256 + threadIdx.x) * 4;
    if (p >= NN) return;
    const int i  = p / WW;
    const int j  = p % WW;                      // multiple of 4
    const int nb = unwalk[(i & ~1)*WW + j];     // 2x4-block base rank
    const int n2 = nb + 2*(i & 1);
    const int c0 = blockIdx.y * (CCH/4);        // 8 channels per block.y
    #pragma unroll
    for (int cc = 0; cc < CCH/4; ++cc) {
        const int c = c0 + cc;
        const f32x2 a  = *reinterpret_cast<const f32x2*>(se + (size_t)c*NN + n2);
        const f32x2 b2 = *reinterpret_cast<const f32x2*>(se + (size_t)c*NN + n2 + 4);
        const float bd = b_deflat[c];
        f32x4 v; v.x = a.x + bd; v.y = a.y + bd; v.z = b2.x + bd; v.w = b2.y + bd;
        *reinterpret_cast<f32x4*>(se_r + (size_t)c*NN + p) = v;
    }
}

// ---- main kernel: R12 structure + 2 independent strips per thread (rows i,
// i+4, same j). Per-instruction coalescing identical to R12; per-wave
// in-flight loads double to ~64 and two independent dep-chains interleave.
template<int SE_RASTER>
__global__ __launch_bounds__(THREADS, 2) void fused_flatten_deflatten(
    const float* __restrict__ latent,    // (B, C, N)
    const float* __restrict__ w_flat,    // (BCH, C)
    const float* __restrict__ b_flat,    // (BCH,)
    const float* __restrict__ w_deflat,  // (C, BCH)
    const float* __restrict__ b_deflat,  // (C,)
    const float* __restrict__ se,        // se_r (ws, bias folded) if SE_RASTER else se
    const int*   __restrict__ unwalk,    // (N,)
    float* __restrict__ recon,           // (B, C, N)
    float* __restrict__ flat_out)        // (B, BCH, N)
{
    const int g    = blockIdx.x;
    const int xcd  = g & (NXCD-1);
    const int idx  = g >> 3;
    const int r    = xcd + NXCD*(idx >> 5);   // chunk: {xcd, xcd+8, xcd+16}
    const int b    = idx & 31;                // batch (inner)
    if (r >= CHUNKS) return;

    __shared__ float s_wf[BCH*CCH];   // [o][c]
    __shared__ float s_wd[CCH*BCH];   // [c][o]
    __shared__ float s_bf[BCH];
    __shared__ float s_bd[CCH];

    const int t = threadIdx.x;
    if (t < BCH*CCH) { s_wf[t] = w_flat[t]; s_wd[t] = w_deflat[t]; }
    if (t < BCH)     s_bf[t] = b_flat[t];
    if (t < CCH)     s_bd[t] = b_deflat[t];
    __syncthreads();

    const int a   = t / 80;            // 0..3
    const int j   = 4*(t%80);          // col (multiple of 4)
    const int i1  = RPC*r + a;         // strip 1 row
    const int i2  = i1 + 4;            // strip 2 row
    if (i1 >= HH) return;
    const bool s2 = (i2 < HH);         // last chunk (r=22): strip 2 off

    const int p1  = i1*WW + j;
    const int p2  = i2*WW + j;
    const int n2a = unwalk[(i1 & ~1)*WW + j] + 2*(i1 & 1);
    const int n2b = s2 ? (unwalk[(i2 & ~1)*WW + j] + 2*(i2 & 1)) : n2a;

    const float* latb1 = latent + (size_t)b * (CCH*NN) + p1;
    const float* latb2 = latent + (size_t)b * (CCH*NN) + p2;

    // ---- pass 1: flat = W_f @ latent + b_f  (two independent chains)
    float acc1[BCH][4], acc2[BCH][4];
    #pragma unroll
    for (int o = 0; o < BCH; ++o) {
        const float bo = s_bf[o];
        #pragma unroll
        for (int k = 0; k < 4; ++k) { acc1[o][k] = bo; acc2[o][k] = bo; }
    }

    #pragma unroll
    for (int c = 0; c < CCH; ++c) {
        const f32x4 x1 = __builtin_nontemporal_load(
            reinterpret_cast<const f32x4*>(latb1 + (size_t)c*NN));
        const f32x4 x2 = s2 ? __builtin_nontemporal_load(
            reinterpret_cast<const f32x4*>(latb2 + (size_t)c*NN))
            : f32x4{0.f,0.f,0.f,0.f};
        #pragma unroll
        for (int o = 0; o < BCH; ++o) {
            const float w = s_wf[o*CCH + c];
            acc1[o][0] += w*x1.x; acc1[o][1] += w*x1.y;
            acc1[o][2] += w*x1.z; acc1[o][3] += w*x1.w;
            acc2[o][0] += w*x2.x; acc2[o][1] += w*x2.y;
            acc2[o][2] += w*x2.z; acc2[o][3] += w*x2.w;
        }
    }

    // ---- flat stores
    float* fb1 = flat_out + (size_t)b * (BCH*NN) + n2a;
    float* fb2 = flat_out + (size_t)b * (BCH*NN) + n2b;
    #pragma unroll
    for (int o = 0; o < BCH; ++o) {
        f32x2 lo1; lo1.x = acc1[o][0]; lo1.y = acc1[o][1];
        f32x2 hi1; hi1.x = acc1[o][2]; hi1.y = acc1[o][3];
        *reinterpret_cast<f32x2*>(fb1 + (size_t)o*NN)     = lo1;
        *reinterpret_cast<f32x2*>(fb1 + (size_t)o*NN + 4) = hi1;
        if (s2) {
            f32x2 lo2; lo2.x = acc2[o][0]; lo2.y = acc2[o][1];
            f32x2 hi2; hi2.x = acc2[o][2]; hi2.y = acc2[o][3];
            *reinterpret_cast<f32x2*>(fb2 + (size_t)o*NN)     = lo2;
            *reinterpret_cast<f32x2*>(fb2 + (size_t)o*NN + 4) = hi2;
        }
    }

    // ---- pass 2: recon = W_d @ flat + (se + b_d)  (two chains)
    float* reconb1 = recon + (size_t)b * (CCH*NN) + p1;
    float* reconb2 = recon + (size_t)b * (CCH*NN) + p2;
    #pragma unroll
    for (int c = 0; c < CCH; ++c) {
        float y0, y1, y2, y3, z0, z1, z2, z3;
        if (SE_RASTER) {
            const f32x4 s4 = *reinterpret_cast<const f32x4*>(se + (size_t)c*NN + p1);
            y0 = s4.x; y1 = s4.y; y2 = s4.z; y3 = s4.w;   // bias pre-folded
            if (s2) {
                const f32x4 u4 = *reinterpret_cast<const f32x4*>(se + (size_t)c*NN + p2);
                z0 = u4.x; z1 = u4.y; z2 = u4.z; z3 = u4.w;
            } else { z0 = z1 = z2 = z3 = 0.f; }
        } else {
            const float bd = s_bd[c];
            const f32x2 a1  = *reinterpret_cast<const f32x2*>(se + (size_t)c*NN + n2a);
            const f32x2 b1  = *reinterpret_cast<const f32x2*>(se + (size_t)c*NN + n2a + 4);
            y0 = bd + a1.x; y1 = bd + a1.y; y2 = bd + b1.x; y3 = bd + b1.y;
            if (s2) {
                const f32x2 a2 = *reinterpret_cast<const f32x2*>(se + (size_t)c*NN + n2b);
                const f32x2 b2v = *reinterpret_cast<const f32x2*>(se + (size_t)c*NN + n2b + 4);
                z0 = bd + a2.x; z1 = bd + a2.y; z2 = bd + b2v.x; z3 = bd + b2v.y;
            } else { z0 = z1 = z2 = z3 = 0.f; }
        }
        #pragma unroll
        for (int o = 0; o < BCH; ++o) {
            const float w = s_wd[c*BCH + o];
            y0 += w*acc1[o][0]; y1 += w*acc1[o][1];
            y2 += w*acc1[o][2]; y3 += w*acc1[o][3];
            z0 += w*acc2[o][0]; z1 += w*acc2[o][1];
            z2 += w*acc2[o][2]; z3 += w*acc2[o][3];
        }
        f32x4 yv; yv.x = y0; yv.y = y1; yv.z = y2; yv.w = y3;
        __builtin_nontemporal_store(yv,
            reinterpret_cast<f32x4*>(reconb1 + (size_t)c*NN));
        if (s2) {
            f32x4 zv; zv.x = z0; zv.y = z1; zv.z = z2; zv.w = z3;
            __builtin_nontemporal_store(zv,
                reinterpret_cast<f32x4*>(reconb2 + (size_t)c*NN));
        }
    }
}

extern "C" void kernel_launch(void* const* d_in, const int* in_sizes, int n_in,
                              void* d_out, int out_size, void* d_ws, size_t ws_size,
                              hipStream_t stream) {
    const float* latent   = (const float*)d_in[0];
    const float* w_flat   = (const float*)d_in[1];
    const float* b_flat   = (const float*)d_in[2];
    const float* w_deflat = (const float*)d_in[3];
    const float* b_deflat = (const float*)d_in[4];
    const float* se       = (const float*)d_in[5];
    const int*   unwalk   = (const int*)d_in[7];   // d_in[6] = walk_idx (unused)

    float* recon = (float*)d_out;
    float* flat  = (float*)d_out + (size_t)BATCH * CCH * NN;

    const size_t se_bytes = (size_t)CCH * NN * sizeof(float);
    dim3 grid(GRID_MAIN);            // 768 blocks (32 pad-exit)
    dim3 block(THREADS);

    if (ws_size >= se_bytes) {
        float* se_r = (float*)d_ws;
        permute_se<<<dim3((NN/4 + 255)/256, 4), dim3(256), 0, stream>>>(
            se, unwalk, b_deflat, se_r);
        fused_flatten_deflatten<1><<<grid, block, 0, stream>>>(
            latent, w_flat, b_flat, w_deflat, b_deflat, se_r, unwalk, recon, flat);
    } else {
        fused_flatten_deflatten<0><<<grid, block, 0, stream>>>(
            latent, w_flat, b_flat, w_deflat, b_deflat, se, unwalk, recon, flat);
    }
}

// Round 14
// 260.913 us; speedup vs baseline: 1.0967x; 1.0967x over previous
//
#include <hip/hip_runtime.h>

#define CCH 32
#define BCH 6
#define HH  180
#define WW  320
#define NN  (HH*WW)             // 57600
#define BATCH 32
#define RPC 8                    // rows per chunk
#define CHUNKS ((HH + RPC - 1)/RPC)   // 23 (last chunk: 4 rows, strip2 guarded off)
#define THREADS 320              // 5 waves; 8 px per thread = 2 strips of 4 px
#define NXCD 8
#define GRID_MAIN (NXCD * 3 * BATCH)  // 768: each XCD gets 3 chunk-slots x 32 b

typedef float f32x2 __attribute__((ext_vector_type(2)));
typedef float f32x4 __attribute__((ext_vector_type(4)));

// ---- kernel A: se_r[c][p] = se[c][walk-strip(p)] + b_deflat[c]
__global__ __launch_bounds__(256) void permute_se(
    const float* __restrict__ se, const int* __restrict__ unwalk,
    const float* __restrict__ b_deflat, float* __restrict__ se_r)
{
    const int p = (blockIdx.x * 256 + threadIdx.x) * 4;
    if (p >= NN) return;
    const int i  = p / WW;
    const int j  = p % WW;                      // multiple of 4
    const int nb = unwalk[(i & ~1)*WW + j];     // 2x4-block base rank
    const int n2 = nb + 2*(i & 1);
    const int c0 = blockIdx.y * (CCH/4);        // 8 channels per block.y
    #pragma unroll
    for (int cc = 0; cc < CCH/4; ++cc) {
        const int c = c0 + cc;
        const f32x2 a  = *reinterpret_cast<const f32x2*>(se + (size_t)c*NN + n2);
        const f32x2 b2 = *reinterpret_cast<const f32x2*>(se + (size_t)c*NN + n2 + 4);
        const float bd = b_deflat[c];
        f32x4 v; v.x = a.x + bd; v.y = a.y + bd; v.z = b2.x + bd; v.w = b2.y + bd;
        *reinterpret_cast<f32x4*>(se_r + (size_t)c*NN + p) = v;
    }
}

// ---- main kernel: 2 independent strips per thread (rows i, i+4, same j).
// NO launch_bounds min-waves arg: R13's (320,2) capped VGPR at 128 and the
// ~250-reg demand spilled to scratch (FETCH+94MB, WRITE+200MB). Loads for
// strip 2 are always-valid (row clamped); only stores are guarded.
template<int SE_RASTER>
__global__ __launch_bounds__(THREADS) void fused_flatten_deflatten(
    const float* __restrict__ latent,    // (B, C, N)
    const float* __restrict__ w_flat,    // (BCH, C)
    const float* __restrict__ b_flat,    // (BCH,)
    const float* __restrict__ w_deflat,  // (C, BCH)
    const float* __restrict__ b_deflat,  // (C,)
    const float* __restrict__ se,        // se_r (ws, bias folded) if SE_RASTER else se
    const int*   __restrict__ unwalk,    // (N,)
    float* __restrict__ recon,           // (B, C, N)
    float* __restrict__ flat_out)        // (B, BCH, N)
{
    const int g    = blockIdx.x;
    const int xcd  = g & (NXCD-1);
    const int idx  = g >> 3;
    const int r    = xcd + NXCD*(idx >> 5);   // chunk: {xcd, xcd+8, xcd+16}
    const int b    = idx & 31;                // batch (inner)
    if (r >= CHUNKS) return;

    __shared__ float s_wf[BCH*CCH];   // [o][c]
    __shared__ float s_wd[CCH*BCH];   // [c][o]
    __shared__ float s_bf[BCH];
    __shared__ float s_bd[CCH];

    const int t = threadIdx.x;
    if (t < BCH*CCH) { s_wf[t] = w_flat[t]; s_wd[t] = w_deflat[t]; }
    if (t < BCH)     s_bf[t] = b_flat[t];
    if (t < CCH)     s_bd[t] = b_deflat[t];
    __syncthreads();

    const int a   = t / 80;            // 0..3
    const int j   = 4*(t%80);          // col (multiple of 4)
    const int i1  = RPC*r + a;         // strip 1 row
    if (i1 >= HH) return;
    const bool s2 = (i1 + 4 < HH);     // last chunk (r=22): strip 2 off
    const int i2  = s2 ? (i1 + 4) : i1;   // clamp: loads always valid

    const int p1  = i1*WW + j;
    const int p2  = i2*WW + j;
    const int n2a = unwalk[(i1 & ~1)*WW + j] + 2*(i1 & 1);
    const int n2b = unwalk[(i2 & ~1)*WW + j] + 2*(i2 & 1);

    const float* latb1 = latent + (size_t)b * (CCH*NN) + p1;
    const float* latb2 = latent + (size_t)b * (CCH*NN) + p2;

    // ---- pass 1: flat = W_f @ latent + b_f  (two independent chains)
    float acc1[BCH][4], acc2[BCH][4];
    #pragma unroll
    for (int o = 0; o < BCH; ++o) {
        const float bo = s_bf[o];
        #pragma unroll
        for (int k = 0; k < 4; ++k) { acc1[o][k] = bo; acc2[o][k] = bo; }
    }

    #pragma unroll
    for (int c = 0; c < CCH; ++c) {
        const f32x4 x1 = __builtin_nontemporal_load(
            reinterpret_cast<const f32x4*>(latb1 + (size_t)c*NN));
        const f32x4 x2 = __builtin_nontemporal_load(
            reinterpret_cast<const f32x4*>(latb2 + (size_t)c*NN));
        #pragma unroll
        for (int o = 0; o < BCH; ++o) {
            const float w = s_wf[o*CCH + c];
            acc1[o][0] += w*x1.x; acc1[o][1] += w*x1.y;
            acc1[o][2] += w*x1.z; acc1[o][3] += w*x1.w;
            acc2[o][0] += w*x2.x; acc2[o][1] += w*x2.y;
            acc2[o][2] += w*x2.z; acc2[o][3] += w*x2.w;
        }
    }

    // ---- flat stores
    float* fb1 = flat_out + (size_t)b * (BCH*NN) + n2a;
    float* fb2 = flat_out + (size_t)b * (BCH*NN) + n2b;
    #pragma unroll
    for (int o = 0; o < BCH; ++o) {
        f32x2 lo1; lo1.x = acc1[o][0]; lo1.y = acc1[o][1];
        f32x2 hi1; hi1.x = acc1[o][2]; hi1.y = acc1[o][3];
        *reinterpret_cast<f32x2*>(fb1 + (size_t)o*NN)     = lo1;
        *reinterpret_cast<f32x2*>(fb1 + (size_t)o*NN + 4) = hi1;
        if (s2) {
            f32x2 lo2; lo2.x = acc2[o][0]; lo2.y = acc2[o][1];
            f32x2 hi2; hi2.x = acc2[o][2]; hi2.y = acc2[o][3];
            *reinterpret_cast<f32x2*>(fb2 + (size_t)o*NN)     = lo2;
            *reinterpret_cast<f32x2*>(fb2 + (size_t)o*NN + 4) = hi2;
        }
    }

    // ---- pass 2: recon = W_d @ flat + (se + b_d)  (two chains)
    float* reconb1 = recon + (size_t)b * (CCH*NN) + p1;
    float* reconb2 = recon + (size_t)b * (CCH*NN) + p2;
    #pragma unroll
    for (int c = 0; c < CCH; ++c) {
        float y0, y1, y2, y3, z0, z1, z2, z3;
        if (SE_RASTER) {
            const f32x4 s4 = *reinterpret_cast<const f32x4*>(se + (size_t)c*NN + p1);
            const f32x4 u4 = *reinterpret_cast<const f32x4*>(se + (size_t)c*NN + p2);
            y0 = s4.x; y1 = s4.y; y2 = s4.z; y3 = s4.w;   // bias pre-folded
            z0 = u4.x; z1 = u4.y; z2 = u4.z; z3 = u4.w;
        } else {
            const float bd = s_bd[c];
            const f32x2 a1  = *reinterpret_cast<const f32x2*>(se + (size_t)c*NN + n2a);
            const f32x2 b1  = *reinterpret_cast<const f32x2*>(se + (size_t)c*NN + n2a + 4);
            const f32x2 a2  = *reinterpret_cast<const f32x2*>(se + (size_t)c*NN + n2b);
            const f32x2 b2v = *reinterpret_cast<const f32x2*>(se + (size_t)c*NN + n2b + 4);
            y0 = bd + a1.x; y1 = bd + a1.y; y2 = bd + b1.x; y3 = bd + b1.y;
            z0 = bd + a2.x; z1 = bd + a2.y; z2 = bd + b2v.x; z3 = bd + b2v.y;
        }
        #pragma unroll
        for (int o = 0; o < BCH; ++o) {
            const float w = s_wd[c*BCH + o];
            y0 += w*acc1[o][0]; y1 += w*acc1[o][1];
            y2 += w*acc1[o][2]; y3 += w*acc1[o][3];
            z0 += w*acc2[o][0]; z1 += w*acc2[o][1];
            z2 += w*acc2[o][2]; z3 += w*acc2[o][3];
        }
        f32x4 yv; yv.x = y0; yv.y = y1; yv.z = y2; yv.w = y3;
        __builtin_nontemporal_store(yv,
            reinterpret_cast<f32x4*>(reconb1 + (size_t)c*NN));
        if (s2) {
            f32x4 zv; zv.x = z0; zv.y = z1; zv.z = z2; zv.w = z3;
            __builtin_nontemporal_store(zv,
                reinterpret_cast<f32x4*>(reconb2 + (size_t)c*NN));
        }
    }
}

extern "C" void kernel_launch(void* const* d_in, const int* in_sizes, int n_in,
                              void* d_out, int out_size, void* d_ws, size_t ws_size,
                              hipStream_t stream) {
    const float* latent   = (const float*)d_in[0];
    const float* w_flat   = (const float*)d_in[1];
    const float* b_flat   = (const float*)d_in[2];
    const float* w_deflat = (const float*)d_in[3];
    const float* b_deflat = (const float*)d_in[4];
    const float* se       = (const float*)d_in[5];
    const int*   unwalk   = (const int*)d_in[7];   // d_in[6] = walk_idx (unused)

    float* recon = (float*)d_out;
    float* flat  = (float*)d_out + (size_t)BATCH * CCH * NN;

    const size_t se_bytes = (size_t)CCH * NN * sizeof(float);
    dim3 grid(GRID_MAIN);            // 768 blocks (32 pad-exit)
    dim3 block(THREADS);

    if (ws_size >= se_bytes) {
        float* se_r = (float*)d_ws;
        permute_se<<<dim3((NN/4 + 255)/256, 4), dim3(256), 0, stream>>>(
            se, unwalk, b_deflat, se_r);
        fused_flatten_deflatten<1><<<grid, block, 0, stream>>>(
            latent, w_flat, b_flat, w_deflat, b_deflat, se_r, unwalk, recon, flat);
    } else {
        fused_flatten_deflatten<0><<<grid, block, 0, stream>>>(
            latent, w_flat, b_flat, w_deflat, b_deflat, se, unwalk, recon, flat);
    }
}

// Round 15
// 118.111 us; speedup vs baseline: 2.4227x; 2.2091x over previous
//
#include <hip/hip_runtime.h>

#define CCH 32
#define BCH 6
#define HH  180
#define WW  320
#define NN  (HH*WW)              // 57600
#define BATCH 32
#define NGROUPS 8                 // batch groups (4 batches each)
#define GPB 4                     // batches per block
#define SLOTS 80                  // f32x4 column-slots per row (320/4)
#define THREADS (SLOTS*GPB)       // 320 threads = 5 waves

typedef float f32x2 __attribute__((ext_vector_type(2)));
typedef float f32x4 __attribute__((ext_vector_type(4)));

// Block = one raster row i x 4 batches. The row's se slice (32c x 320px,
// 40KB) is staged ONCE into LDS (raster order, b_deflat folded), then each
// thread runs the R12 full-unroll body with pass-2 se reads from LDS.
// This removes the ~236MB/replay L1<->L2 se stream (the hidden third of
// fabric traffic) and the permute pre-pass + its dependency bubble.
__global__ __launch_bounds__(THREADS) void fused_flatten_deflatten(
    const float* __restrict__ latent,    // (B, C, N)
    const float* __restrict__ w_flat,    // (BCH, C)
    const float* __restrict__ b_flat,    // (BCH,)
    const float* __restrict__ w_deflat,  // (C, BCH)
    const float* __restrict__ b_deflat,  // (C,)
    const float* __restrict__ se,        // (1, C, N) walk domain
    const int*   __restrict__ unwalk,    // (N,)
    float* __restrict__ recon,           // (B, C, N)
    float* __restrict__ flat_out)        // (B, BCH, N)
{
    __shared__ float s_se[CCH*WW];    // [c][320] raster px of row i, bias folded
    __shared__ float s_wf[BCH*CCH];   // [o][c]
    __shared__ float s_wd[CCH*BCH];   // [c][o]
    __shared__ float s_bf[BCH];

    const int t   = threadIdx.x;
    const int bx  = blockIdx.x;
    const int i   = bx / NGROUPS;      // row 0..179
    const int grp = bx % NGROUPS;      // group fast: co-running blocks share row

    if (t < BCH*CCH) { s_wf[t] = w_flat[t]; s_wd[t] = w_deflat[t]; }
    if (t < BCH)     s_bf[t] = b_flat[t];

    const int sl = t % SLOTS;          // column slot: cols 4sl..4sl+3
    const int bg = t / SLOTS;          // 0..3
    const int j  = 4*sl;
    const int p  = i*WW + j;

    // strip ranks {n2, n2+1, n2+4, n2+5} (2x4 z-block identity, row-parity)
    const int nb = unwalk[(i & ~1)*WW + j];
    const int n2 = nb + 2*(i & 1);

    // ---- stage se row-slice into LDS: thread covers its own slot, channels
    //      c = bg + 4k (8 items). LDS write f32x4 at byte c*1280 + sl*16.
    #pragma unroll
    for (int k = 0; k < 8; ++k) {
        const int c = bg + 4*k;
        const f32x2 a = *reinterpret_cast<const f32x2*>(se + (size_t)c*NN + n2);
        const f32x2 d = *reinterpret_cast<const f32x2*>(se + (size_t)c*NN + n2 + 4);
        const float bd = b_deflat[c];
        f32x4 v; v.x = a.x + bd; v.y = a.y + bd; v.z = d.x + bd; v.w = d.y + bd;
        *reinterpret_cast<f32x4*>(&s_se[c*WW + j]) = v;
    }
    __syncthreads();

    const int b = grp*GPB + bg;        // batch
    const float* latb   = latent + (size_t)b * (CCH*NN) + p;
    float*       reconb = recon  + (size_t)b * (CCH*NN) + p;

    // ---- pass 1: flat = W_f @ latent + b_f  (full unroll: deep in-flight)
    float acc[BCH][4];
    #pragma unroll
    for (int o = 0; o < BCH; ++o) {
        const float bo = s_bf[o];
        acc[o][0] = bo; acc[o][1] = bo; acc[o][2] = bo; acc[o][3] = bo;
    }

    #pragma unroll
    for (int c = 0; c < CCH; ++c) {
        const f32x4 x = __builtin_nontemporal_load(
            reinterpret_cast<const f32x4*>(latb + (size_t)c*NN));
        #pragma unroll
        for (int o = 0; o < BCH; ++o) {
            const float w = s_wf[o*CCH + c];
            acc[o][0] += w*x.x; acc[o][1] += w*x.y;
            acc[o][2] += w*x.z; acc[o][3] += w*x.w;
        }
    }

    // ---- flat stores: ranks n2,n2+1 (cols 0,1) and n2+4,n2+5 (cols 2,3)
    float* fb = flat_out + (size_t)b * (BCH*NN) + n2;
    #pragma unroll
    for (int o = 0; o < BCH; ++o) {
        f32x2 lo; lo.x = acc[o][0]; lo.y = acc[o][1];
        f32x2 hi; hi.x = acc[o][2]; hi.y = acc[o][3];
        *reinterpret_cast<f32x2*>(fb + (size_t)o*NN)     = lo;
        *reinterpret_cast<f32x2*>(fb + (size_t)o*NN + 4) = hi;
    }

    // ---- pass 2: recon = W_d @ flat + (se + b_d)   (se from LDS)
    #pragma unroll
    for (int c = 0; c < CCH; ++c) {
        const f32x4 s4 = *reinterpret_cast<const f32x4*>(&s_se[c*WW + j]);
        float y0 = s4.x, y1 = s4.y, y2 = s4.z, y3 = s4.w;  // bias pre-folded
        #pragma unroll
        for (int o = 0; o < BCH; ++o) {
            const float w = s_wd[c*BCH + o];
            y0 += w*acc[o][0]; y1 += w*acc[o][1];
            y2 += w*acc[o][2]; y3 += w*acc[o][3];
        }
        f32x4 yv; yv.x = y0; yv.y = y1; yv.z = y2; yv.w = y3;
        __builtin_nontemporal_store(yv,
            reinterpret_cast<f32x4*>(reconb + (size_t)c*NN));
    }
}

extern "C" void kernel_launch(void* const* d_in, const int* in_sizes, int n_in,
                              void* d_out, int out_size, void* d_ws, size_t ws_size,
                              hipStream_t stream) {
    const float* latent   = (const float*)d_in[0];
    const float* w_flat   = (const float*)d_in[1];
    const float* b_flat   = (const float*)d_in[2];
    const float* w_deflat = (const float*)d_in[3];
    const float* b_deflat = (const float*)d_in[4];
    const float* se       = (const float*)d_in[5];
    const int*   unwalk   = (const int*)d_in[7];   // d_in[6] = walk_idx (unused)

    float* recon = (float*)d_out;
    float* flat  = (float*)d_out + (size_t)BATCH * CCH * NN;

    dim3 grid(HH * NGROUPS);         // 180 * 8 = 1440 blocks
    dim3 block(THREADS);
    fused_flatten_deflatten<<<grid, block, 0, stream>>>(
        latent, w_flat, b_flat, w_deflat, b_deflat, se, unwalk, recon, flat);
}